// Round 1
// baseline (2466.556 us; speedup 1.0000x reference)
//
#include <hip/hip_runtime.h>

// WaveNetX forward, fp32. B=64, L=2048, V=30, E=128, G=8, C=64, F=128, O=30, K=2, ND=9.
#define Bz 64
#define Lz 2048
#define Vz 30
#define Ez 128
#define Gz 8
#define Cz 64
#define Fz 128
#define Oz 30
#define NDz 9

__device__ __forceinline__ float fsig(float x) {
    x = fminf(fmaxf(x, -30.f), 30.f);
    return __builtin_amdgcn_rcpf(1.f + __expf(-x));
}
__device__ __forceinline__ float ftanh(float x) {
    x = fminf(fmaxf(x, -15.f), 15.f);
    float e = __expf(2.f * x);
    return (e - 1.f) * __builtin_amdgcn_rcpf(e + 1.f);
}

// ---------------------------------------------------------------------------
// Pack weights into layer-friendly layouts + tiny per-token projection tables.
//  WP  [ND][C][C] float4 = (wf_tap1, wf_tap0, wg_tap1, wg_tap0)
//  WrP [ND][C][C/4] float4 (skip matmul rows)
//  proj0/proj1 [V][C]: token -> initial-conv contribution (row 0 zeroed)
//  W1P [F][C/4] float4, W2P [O][F/4] float4
// ---------------------------------------------------------------------------
__global__ void pack_k(const float* __restrict__ w_f, const float* __restrict__ w_g,
                       const float* __restrict__ w_res, const float* __restrict__ w_fin1,
                       const float* __restrict__ w_fin2, const float* __restrict__ w_causal,
                       const float* __restrict__ table,
                       float4* __restrict__ WP, float4* __restrict__ WrP,
                       float* __restrict__ proj0, float* __restrict__ proj1,
                       float4* __restrict__ W1P, float4* __restrict__ W2P) {
    int tid = blockIdx.x * 256 + threadIdx.x;
    if (tid < NDz * Cz * Cz) {                      // 36864: WP
        int i = tid >> 12, r = tid & 4095, c = r >> 6, k = r & 63;
        int base = ((i * Cz + c) * Cz + k) * 2;
        WP[tid] = make_float4(w_f[base + 1], w_f[base], w_g[base + 1], w_g[base]);
        return;
    }
    tid -= NDz * Cz * Cz;
    if (tid < NDz * Cz * 16) {                      // 9216: WrP
        int i = tid >> 10, r = tid & 1023, o = r >> 4, c4 = r & 15;
        const float* p = w_res + (i * Cz + o) * Cz + c4 * 4;
        WrP[tid] = make_float4(p[0], p[1], p[2], p[3]);
        return;
    }
    tid -= NDz * Cz * 16;
    if (tid < Vz * Cz) {                            // 1920: proj tables
        int v = tid >> 6, c = tid & 63;
        float s0 = 0.f, s1 = 0.f;
        if (v != 0) {                               // padding_idx=0 -> zero row
            for (int e = 0; e < Ez; e++) {
                float tv = table[v * Ez + e];
                s0 += w_causal[(c * Ez + e) * 2 + 0] * tv;
                s1 += w_causal[(c * Ez + e) * 2 + 1] * tv;
            }
        }
        proj0[tid] = s0; proj1[tid] = s1;
        return;
    }
    tid -= Vz * Cz;
    if (tid < Fz * 16) {                            // 2048: W1P
        int f = tid >> 4, c4 = tid & 15;
        const float* p = w_fin1 + f * Cz + c4 * 4;
        W1P[tid] = make_float4(p[0], p[1], p[2], p[3]);
        return;
    }
    tid -= Fz * 16;
    if (tid < Oz * 32) {                            // 960: W2P
        int o = tid >> 5, f4 = tid & 31;
        const float* p = w_fin2 + o * Fz + f4 * 4;
        W2P[tid] = make_float4(p[0], p[1], p[2], p[3]);
    }
}

// ---------------------------------------------------------------------------
// Global-conditioning vectors: hh[i][fg][b][c] = b_(f/g)[i,c] + bl_(f/g)[i,c]
//                                         + sum_j emb_g[b,j] * wl_(f/g)[i][c,j]
// One block per (i, fg, b); 256 threads = 64 c x 4 e-quarters.
// ---------------------------------------------------------------------------
__global__ __launch_bounds__(256) void hcomp_k(
    const int* __restrict__ gin, const float* __restrict__ table,
    const float* __restrict__ wl_f, const float* __restrict__ wl_g,
    const float* __restrict__ b_f, const float* __restrict__ b_g,
    const float* __restrict__ bl_f, const float* __restrict__ bl_g,
    float* __restrict__ hh) {
    __shared__ alignas(16) float sg[Gz * Ez];
    __shared__ float sred[256];
    int blk = blockIdx.x;
    int i = blk >> 7, r = blk & 127, fg = r >> 6, b = r & 63;
    int tx = threadIdx.x;
    for (int idx = tx; idx < Gz * Ez; idx += 256) {
        int g = idx >> 7, e = idx & 127;
        int v = gin[b * Gz + g];
        sg[idx] = v ? table[v * Ez + e] : 0.f;
    }
    __syncthreads();
    const float* wl = (fg ? wl_g : wl_f) + ((size_t)i * Cz) * (Gz * Ez);
    int c = tx & 63, q = tx >> 6;
    const float4* wl4 = (const float4*)(wl + (size_t)c * (Gz * Ez) + q * 256);
    const float4* sg4 = (const float4*)(sg + q * 256);
    float p = 0.f;
#pragma unroll 4
    for (int e4 = 0; e4 < 64; e4++) {
        float4 a = wl4[e4]; float4 g4 = sg4[e4];
        p += a.x * g4.x + a.y * g4.y + a.z * g4.z + a.w * g4.w;
    }
    sred[tx] = p;
    __syncthreads();
    if (tx < 64) {
        const float* bb = (fg ? b_g : b_f) + i * Cz;
        const float* bl = (fg ? bl_g : bl_f) + i * Cz;
        hh[((size_t)(i * 2 + fg) * Bz + b) * Cz + tx] =
            bb[tx] + bl[tx] + sred[tx] + sred[64 + tx] + sred[128 + tx] + sred[192 + tx];
    }
}

// ---------------------------------------------------------------------------
// Initial causal conv (dilation 1) as a pure token-table lookup.
// res[b,c,t] = b_causal[c] + proj1[tok[t],c] + (t>0 ? proj0[tok[t-1],c] : 0)
// ---------------------------------------------------------------------------
__global__ __launch_bounds__(256) void init_k(
    const int* __restrict__ tok, const float* __restrict__ b_causal,
    const float* __restrict__ proj0, const float* __restrict__ proj1,
    float* __restrict__ res) {
    __shared__ float sp0[Vz * 65], sp1[Vz * 65];   // pad 65: avoid stride-64 bank clash
    int tx = threadIdx.x;
    for (int idx = tx; idx < Vz * 64; idx += 256) {
        int v = idx >> 6, c = idx & 63;
        sp0[v * 65 + c] = proj0[idx];
        sp1[v * 65 + c] = proj1[idx];
    }
    __syncthreads();
    int b = blockIdx.y;
    int t = blockIdx.x * 256 + tx;
    int v1 = tok[b * Lz + t];
    int v0 = (t > 0) ? tok[b * Lz + t - 1] : 0;
    bool h0 = t > 0;
    float* rp = res + ((size_t)b * Cz) * Lz + t;
#pragma unroll 1
    for (int c = 0; c < Cz; c++) {
        float r = b_causal[c] + sp1[v1 * 65 + c] + (h0 ? sp0[v0 * 65 + c] : 0.f);
        rp[(size_t)c * Lz] = r;
    }
}

// ---------------------------------------------------------------------------
// One dilated gated residual layer. Thread = one position t.
// accf/accg[64] in VGPRs; weights via uniform (scalar-pipe) float4 loads.
// Double-buffered res (rin -> rout) to avoid cross-block read/write race on
// the t-d taps. skips updated in place (own positions only).
// ---------------------------------------------------------------------------
__global__ __launch_bounds__(256, 2) void layer_k(
    const float* __restrict__ rin, float* __restrict__ rout,
    float* __restrict__ skips,
    const float4* __restrict__ WP, const float4* __restrict__ WrP,
    const float* __restrict__ hh, const float* __restrict__ b_res,
    int i, int d, int first) {
    int tx = threadIdx.x;
    int b = blockIdx.y;
    int t = blockIdx.x * 256 + tx;
    const float* resb = rin + ((size_t)b * Cz) * Lz + t;
    bool ok = (t >= d);
    const float* resbB = ok ? (resb - d) : resb;    // always-valid address
    const float* hf = hh + ((size_t)(i * 2 + 0) * Bz + b) * Cz;
    const float* hg = hh + ((size_t)(i * 2 + 1) * Bz + b) * Cz;

    float accf[Cz], accg[Cz];
#pragma unroll
    for (int c = 0; c < Cz; c++) { accf[c] = hf[c]; accg[c] = hg[c]; }

    const float4* wp = WP + (size_t)i * (Cz * Cz);
#pragma unroll 1
    for (int k0 = 0; k0 < Cz; k0 += 4) {
        float xa[4], xb[4];
#pragma unroll
        for (int j = 0; j < 4; j++) {
            xa[j] = resb[(size_t)(k0 + j) * Lz];
            float v = resbB[(size_t)(k0 + j) * Lz];
            xb[j] = ok ? v : 0.f;
        }
#pragma unroll
        for (int c = 0; c < Cz; c++) {
#pragma unroll
            for (int j = 0; j < 4; j++) {
                float4 w = wp[c * Cz + k0 + j];     // uniform -> s_load_dwordx4
                accf[c] += w.x * xa[j] + w.y * xb[j];
                accg[c] += w.z * xa[j] + w.w * xb[j];
            }
        }
    }

    float z[Cz];
#pragma unroll
    for (int c = 0; c < Cz; c++) z[c] = ftanh(accf[c]) * fsig(accg[c]);

    const float4* wr = WrP + (size_t)i * (Cz * 16);
    const float* br = b_res + i * Cz;
    size_t idx0 = ((size_t)b * Cz) * Lz + t;
#pragma unroll 1
    for (int o = 0; o < Cz; o++) {
        float s = br[o];
#pragma unroll
        for (int c4 = 0; c4 < 16; c4++) {
            float4 w = wr[o * 16 + c4];
            s += w.x * z[c4 * 4 + 0] + w.y * z[c4 * 4 + 1] +
                 w.z * z[c4 * 4 + 2] + w.w * z[c4 * 4 + 3];
        }
        size_t idx = idx0 + (size_t)o * Lz;
        rout[idx] = resb[(size_t)o * Lz] + s;
        float old = first ? 0.f : skips[idx];
        skips[idx] = old + s;
    }
}

// ---------------------------------------------------------------------------
// Head: out = W2 @ relu(W1 @ relu(skips) + b1) + b2. Thread = one position.
// ---------------------------------------------------------------------------
__global__ __launch_bounds__(256, 2) void final_k(
    const float* __restrict__ skips,
    const float4* __restrict__ W1P, const float4* __restrict__ W2P,
    const float* __restrict__ b_fin1, const float* __restrict__ b_fin2,
    float* __restrict__ out) {
    int tx = threadIdx.x;
    int b = blockIdx.y;
    int t = blockIdx.x * 256 + tx;
    const float* sk = skips + ((size_t)b * Cz) * Lz + t;

    float mid[Fz];
#pragma unroll
    for (int f = 0; f < Fz; f++) mid[f] = b_fin1[f];

#pragma unroll 1
    for (int c0 = 0; c0 < Cz; c0 += 4) {
        float x0 = fmaxf(sk[(size_t)(c0 + 0) * Lz], 0.f);
        float x1 = fmaxf(sk[(size_t)(c0 + 1) * Lz], 0.f);
        float x2 = fmaxf(sk[(size_t)(c0 + 2) * Lz], 0.f);
        float x3 = fmaxf(sk[(size_t)(c0 + 3) * Lz], 0.f);
        int c4 = c0 >> 2;
#pragma unroll
        for (int f = 0; f < Fz; f++) {
            float4 w = W1P[f * 16 + c4];
            mid[f] += w.x * x0 + w.y * x1 + w.z * x2 + w.w * x3;
        }
    }
#pragma unroll
    for (int f = 0; f < Fz; f++) mid[f] = fmaxf(mid[f], 0.f);

    float* op = out + ((size_t)b * Oz) * Lz + t;
#pragma unroll 1
    for (int o = 0; o < Oz; o++) {
        float s = b_fin2[o];
#pragma unroll
        for (int f4 = 0; f4 < 32; f4++) {
            float4 w = W2P[o * 32 + f4];
            s += w.x * mid[f4 * 4 + 0] + w.y * mid[f4 * 4 + 1] +
                 w.z * mid[f4 * 4 + 2] + w.w * mid[f4 * 4 + 3];
        }
        op[(size_t)o * Lz] = s;
    }
}

// ---------------------------------------------------------------------------
extern "C" void kernel_launch(void* const* d_in, const int* in_sizes, int n_in,
                              void* d_out, int out_size, void* d_ws, size_t ws_size,
                              hipStream_t stream) {
    const int*   tok      = (const int*)d_in[0];
    const int*   gin      = (const int*)d_in[1];
    const float* table    = (const float*)d_in[2];
    const float* w_causal = (const float*)d_in[3];
    const float* b_causal = (const float*)d_in[4];
    const float* w_f      = (const float*)d_in[5];
    const float* b_f      = (const float*)d_in[6];
    const float* w_g      = (const float*)d_in[7];
    const float* b_g      = (const float*)d_in[8];
    const float* wl_f     = (const float*)d_in[9];
    const float* bl_f     = (const float*)d_in[10];
    const float* wl_g     = (const float*)d_in[11];
    const float* bl_g     = (const float*)d_in[12];
    const float* w_res    = (const float*)d_in[13];
    const float* b_res    = (const float*)d_in[14];
    const float* w_fin1   = (const float*)d_in[15];
    const float* b_fin1   = (const float*)d_in[16];
    const float* w_fin2   = (const float*)d_in[17];
    const float* b_fin2   = (const float*)d_in[18];
    float* out = (float*)d_out;

    // workspace layout (floats)
    float* ws = (float*)d_ws;
    const size_t NRES = (size_t)Bz * Cz * Lz;       // 8388608
    float* resA  = ws;
    float* resB  = ws + NRES;
    float* skips = ws + 2 * NRES;
    float* base  = ws + 3 * NRES;
    float4* WP   = (float4*)(base);                  // 36864 float4
    float4* WrP  = (float4*)(base + 147456);         // 9216 float4
    float*  hh   = base + 147456 + 36864;            // 73728 floats
    float*  proj0 = hh + 73728;                      // 1920
    float*  proj1 = proj0 + 1920;                    // 1920
    float4* W1P  = (float4*)(proj1 + 1920);          // 2048 float4
    float4* W2P  = (float4*)(proj1 + 1920 + 8192);   // 960 float4

    pack_k<<<200, 256, 0, stream>>>(w_f, w_g, w_res, w_fin1, w_fin2, w_causal, table,
                                    WP, WrP, proj0, proj1, W1P, W2P);
    hcomp_k<<<NDz * 2 * Bz, 256, 0, stream>>>(gin, table, wl_f, wl_g,
                                              b_f, b_g, bl_f, bl_g, hh);
    init_k<<<dim3(Lz / 256, Bz), 256, 0, stream>>>(tok, b_causal, proj0, proj1, resA);

    float* rin = resA;
    float* rout = resB;
    for (int i = 0; i < NDz; i++) {
        int d = 2 << i;                              // 2,4,...,512
        layer_k<<<dim3(Lz / 256, Bz), 256, 0, stream>>>(rin, rout, skips, WP, WrP,
                                                        hh, b_res, i, d, i == 0);
        float* tmp = rin; rin = rout; rout = tmp;
    }
    final_k<<<dim3(Lz / 256, Bz), 256, 0, stream>>>(skips, W1P, W2P, b_fin1, b_fin2, out);
}

// Round 2
// 517.979 us; speedup vs baseline: 4.7619x; 4.7619x over previous
//
#include <hip/hip_runtime.h>
#include <stdint.h>

// WaveNetX forward. B=64, L=2048, V=30, E=128, G=8, C=64, F=128, O=30, K=2, ND=9.
// R1: layers + head as bf16 MFMA GEMMs; skips buffer eliminated (skips = resF - res0).
#define Bz 64
#define Lz 2048
#define Vz 30
#define Ez 128
#define Gz 8
#define Cz 64
#define Fz 128
#define Oz 30
#define NDz 9

typedef __attribute__((ext_vector_type(8))) short short8;     // 8 bf16 = 4 VGPR
typedef __attribute__((ext_vector_type(16))) float floatx16;  // 32x32 C/D

__device__ __forceinline__ uint16_t f2bf(float f) {           // RNE f32->bf16
    uint32_t u = __float_as_uint(f);
    u += 0x7fffu + ((u >> 16) & 1u);
    return (uint16_t)(u >> 16);
}
__device__ __forceinline__ float fsig(float x) {
    x = fminf(fmaxf(x, -30.f), 30.f);
    return __builtin_amdgcn_rcpf(1.f + __expf(-x));
}
__device__ __forceinline__ float ftanh(float x) {
    x = fminf(fmaxf(x, -15.f), 15.f);
    float e = __expf(2.f * x);
    return (e - 1.f) * __builtin_amdgcn_rcpf(e + 1.f);
}

// ---------------------------------------------------------------------------
// Pack: WB[i][ch(128)][k(128)] bf16  (ch: 0-63 f, 64-127 g; k: 0-63 tap t (w[..,1]),
//       64-127 tap t-d (w[..,0])).  WrB[i][o][c] bf16.  W1B[f][c], W2B[o(32,pad0)][f].
//       proj0/proj1[V][C] fp32: token -> initial-conv contribution.
// ---------------------------------------------------------------------------
__global__ void pack_k(const float* __restrict__ w_f, const float* __restrict__ w_g,
                       const float* __restrict__ w_res, const float* __restrict__ w_fin1,
                       const float* __restrict__ w_fin2, const float* __restrict__ w_causal,
                       const float* __restrict__ table,
                       uint16_t* __restrict__ WB, uint16_t* __restrict__ WrB,
                       uint16_t* __restrict__ W1B, uint16_t* __restrict__ W2B,
                       float* __restrict__ proj0, float* __restrict__ proj1) {
    int tid = blockIdx.x * 256 + threadIdx.x;
    if (tid < NDz * 128 * 128) {
        int i = tid >> 14, rem = tid & 16383, ch = rem >> 7, k = rem & 127;
        int kin = k & 63, tap = (k < 64) ? 1 : 0;
        float v = (ch < 64) ? w_f[((i * Cz + ch) * Cz + kin) * 2 + tap]
                            : w_g[((i * Cz + (ch - 64)) * Cz + kin) * 2 + tap];
        WB[tid] = f2bf(v);
        return;
    }
    tid -= NDz * 128 * 128;
    if (tid < NDz * 64 * 64) { WrB[tid] = f2bf(w_res[tid]); return; }   // same layout
    tid -= NDz * 64 * 64;
    if (tid < Fz * Cz) { W1B[tid] = f2bf(w_fin1[tid]); return; }        // same layout
    tid -= Fz * Cz;
    if (tid < 32 * Fz) {
        int o = tid >> 7, f = tid & 127;
        W2B[tid] = f2bf(o < Oz ? w_fin2[o * Fz + f] : 0.f);
        return;
    }
    tid -= 32 * Fz;
    if (tid < Vz * Cz) {
        int v = tid >> 6, c = tid & 63;
        float s0 = 0.f, s1 = 0.f;
        if (v != 0) {
            for (int e = 0; e < Ez; e++) {
                float tv = table[v * Ez + e];
                s0 += w_causal[(c * Ez + e) * 2 + 0] * tv;
                s1 += w_causal[(c * Ez + e) * 2 + 1] * tv;
            }
        }
        proj0[tid] = s0; proj1[tid] = s1;
    }
}

// ---------------------------------------------------------------------------
// Global conditioning: hh[(i*2+fg)*B + b][c] (fp32, biases folded in)
// ---------------------------------------------------------------------------
__global__ __launch_bounds__(256) void hcomp_k(
    const int* __restrict__ gin, const float* __restrict__ table,
    const float* __restrict__ wl_f, const float* __restrict__ wl_g,
    const float* __restrict__ b_f, const float* __restrict__ b_g,
    const float* __restrict__ bl_f, const float* __restrict__ bl_g,
    float* __restrict__ hh) {
    __shared__ alignas(16) float sg[Gz * Ez];
    __shared__ float sred[256];
    int blk = blockIdx.x;
    int i = blk >> 7, r = blk & 127, fg = r >> 6, b = r & 63;
    int tx = threadIdx.x;
    for (int idx = tx; idx < Gz * Ez; idx += 256) {
        int g = idx >> 7, e = idx & 127;
        int v = gin[b * Gz + g];
        sg[idx] = v ? table[v * Ez + e] : 0.f;
    }
    __syncthreads();
    const float* wl = (fg ? wl_g : wl_f) + ((size_t)i * Cz) * (Gz * Ez);
    int c = tx & 63, q = tx >> 6;
    const float4* wl4 = (const float4*)(wl + (size_t)c * (Gz * Ez) + q * 256);
    const float4* sg4 = (const float4*)(sg + q * 256);
    float p = 0.f;
#pragma unroll 4
    for (int e4 = 0; e4 < 64; e4++) {
        float4 a = wl4[e4]; float4 g4 = sg4[e4];
        p += a.x * g4.x + a.y * g4.y + a.z * g4.z + a.w * g4.w;
    }
    sred[tx] = p;
    __syncthreads();
    if (tx < 64) {
        const float* bb = (fg ? b_g : b_f) + i * Cz;
        const float* bl = (fg ? bl_g : bl_f) + i * Cz;
        hh[((size_t)(i * 2 + fg) * Bz + b) * Cz + tx] =
            bb[tx] + bl[tx] + sred[tx] + sred[64 + tx] + sred[128 + tx] + sred[192 + tx];
    }
}

// ---------------------------------------------------------------------------
// Initial conv as token lookup; res layout [b][t][c].
// 256 thr = 16 t x 16 c-quads; proj rows are L1-resident (7.5 KB).
// ---------------------------------------------------------------------------
__global__ __launch_bounds__(256) void init_k(
    const int* __restrict__ tok, const float* __restrict__ b_causal,
    const float* __restrict__ proj0, const float* __restrict__ proj1,
    float* __restrict__ res) {
    int tx = threadIdx.x;
    int q = tx & 15, tl = tx >> 4;
    int b = blockIdx.y;
    int t = blockIdx.x * 16 + tl;
    int v1 = tok[b * Lz + t];
    int v0 = (t > 0) ? tok[b * Lz + t - 1] : 0;   // proj0 row 0 is zero -> t=0 ok
    float4 p1 = ((const float4*)(proj1 + v1 * Cz))[q];
    float4 p0 = ((const float4*)(proj0 + v0 * Cz))[q];
    float4 bc = ((const float4*)b_causal)[q];
    float4 r;
    r.x = p1.x + p0.x + bc.x; r.y = p1.y + p0.y + bc.y;
    r.z = p1.z + p0.z + bc.z; r.w = p1.w + p0.w + bc.w;
    ((float4*)(res + ((size_t)(b * Lz + t)) * Cz))[q] = r;
}

// ---------------------------------------------------------------------------
// One layer as MFMA GEMMs. Block = 128 positions x 1 batch, 4 waves.
// GEMM1: [pos(128) x ch(128)] = X[pos x 128k] * Wcat^T ; gate; 
// GEMM2: [pos x 64] = z * Wr^T ; rout = rin + skip + b_res.  No skips buffer.
// ---------------------------------------------------------------------------
__global__ __launch_bounds__(256, 3) void layer_k(
    const float* __restrict__ rin, float* __restrict__ rout,
    const uint16_t* __restrict__ WBl, const uint16_t* __restrict__ WrBl,
    const float* __restrict__ hh, const float* __restrict__ b_res,
    int i, int d) {
    __shared__ __align__(16) uint16_t X[128 * 136];   // [pos][k], pad to 136
    __shared__ __align__(16) uint16_t Z[128 * 72];    // [pos][ch], pad to 72
    int tx = threadIdx.x;
    int b = blockIdx.y, t0 = blockIdx.x * 128;
    const float* rbase = rin + ((size_t)b * Lz) * Cz;

    // stage X: k<64 = res[t][c], k>=64 = res[t-d][c] (or 0)
#pragma unroll
    for (int it = 0; it < 8; it++) {
        int id = it * 256 + tx, p = id >> 4, q = id & 15;
        float4 v = ((const float4*)(rbase + (size_t)(t0 + p) * Cz))[q];
        uint32_t lo = f2bf(v.x) | ((uint32_t)f2bf(v.y) << 16);
        uint32_t hi = f2bf(v.z) | ((uint32_t)f2bf(v.w) << 16);
        *(uint2*)(X + p * 136 + q * 4) = make_uint2(lo, hi);
    }
#pragma unroll
    for (int it = 0; it < 8; it++) {
        int id = it * 256 + tx, p = id >> 4, q = id & 15;
        int t = t0 + p;
        float4 v = make_float4(0.f, 0.f, 0.f, 0.f);
        if (t >= d) v = ((const float4*)(rbase + (size_t)(t - d) * Cz))[q];
        uint32_t lo = f2bf(v.x) | ((uint32_t)f2bf(v.y) << 16);
        uint32_t hi = f2bf(v.z) | ((uint32_t)f2bf(v.w) << 16);
        *(uint2*)(X + p * 136 + 64 + q * 4) = make_uint2(lo, hi);
    }
    __syncthreads();

    int lane = tx & 63, wave = tx >> 6;
    int col = lane & 31, kh = (lane >> 5) * 8;
    int prow = wave * 32 + col;

    floatx16 a0 = {}, a1 = {}, a2 = {}, a3 = {};
    const uint16_t* Ar = X + prow * 136 + kh;
#pragma unroll
    for (int ks = 0; ks < 8; ks++) {
        short8 a = *(const short8*)(Ar + ks * 16);
        const uint16_t* Bw = WBl + col * 128 + ks * 16 + kh;
        a0 = __builtin_amdgcn_mfma_f32_32x32x16_bf16(a, *(const short8*)(Bw + 0 * 32 * 128), a0, 0, 0, 0);
        a1 = __builtin_amdgcn_mfma_f32_32x32x16_bf16(a, *(const short8*)(Bw + 1 * 32 * 128), a1, 0, 0, 0);
        a2 = __builtin_amdgcn_mfma_f32_32x32x16_bf16(a, *(const short8*)(Bw + 2 * 32 * 128), a2, 0, 0, 0);
        a3 = __builtin_amdgcn_mfma_f32_32x32x16_bf16(a, *(const short8*)(Bw + 3 * 32 * 128), a3, 0, 0, 0);
    }

    // gate: nt 0,1 = f channels, nt 2,3 = g channels
    const float* hfp = hh + ((size_t)(i * 2 + 0) * Bz + b) * Cz;
    const float* hgp = hh + ((size_t)(i * 2 + 1) * Bz + b) * Cz;
    float hf0 = hfp[col], hg0 = hgp[col];
    float hf1 = hfp[32 + col], hg1 = hgp[32 + col];
    int rrow = wave * 32 + 4 * (lane >> 5);
#pragma unroll
    for (int r = 0; r < 16; r++) {
        int pos = rrow + (r & 3) + 8 * (r >> 2);
        float z0 = ftanh(a0[r] + hf0) * fsig(a2[r] + hg0);
        float z1 = ftanh(a1[r] + hf1) * fsig(a3[r] + hg1);
        Z[pos * 72 + col] = f2bf(z0);
        Z[pos * 72 + 32 + col] = f2bf(z1);
    }
    __syncthreads();

    floatx16 s0 = {}, s1 = {};
    const uint16_t* Zr = Z + prow * 72 + kh;
#pragma unroll
    for (int ks = 0; ks < 4; ks++) {
        short8 a = *(const short8*)(Zr + ks * 16);
        s0 = __builtin_amdgcn_mfma_f32_32x32x16_bf16(a, *(const short8*)(WrBl + col * 64 + ks * 16 + kh), s0, 0, 0, 0);
        s1 = __builtin_amdgcn_mfma_f32_32x32x16_bf16(a, *(const short8*)(WrBl + (32 + col) * 64 + ks * 16 + kh), s1, 0, 0, 0);
    }
    const float* brp = b_res + i * Cz;
    float br0 = brp[col], br1 = brp[32 + col];
    float* ro = rout + ((size_t)b * Lz) * Cz;
#pragma unroll
    for (int r = 0; r < 16; r++) {
        int pos = rrow + (r & 3) + 8 * (r >> 2);
        size_t off = (size_t)(t0 + pos) * Cz + col;
        ro[off] = rbase[off] + s0[r] + br0;
        ro[off + 32] = rbase[off + 32] + s1[r] + br1;
    }
}

// ---------------------------------------------------------------------------
// Head: s = relu(resF - res0); mid = relu(W1 s + b1); out = W2 mid + b2.
// Same block structure; out written [b][o][t] (L2 merges the o-strided lines).
// ---------------------------------------------------------------------------
__global__ __launch_bounds__(256, 3) void final_k(
    const float* __restrict__ res0, const float* __restrict__ resF,
    const uint16_t* __restrict__ W1B, const uint16_t* __restrict__ W2B,
    const float* __restrict__ b_fin1, const float* __restrict__ b_fin2,
    float* __restrict__ out) {
    __shared__ __align__(16) uint16_t S[128 * 72];
    __shared__ __align__(16) uint16_t Mi[128 * 136];
    int tx = threadIdx.x;
    int b = blockIdx.y, t0 = blockIdx.x * 128;
    const float* r0 = res0 + ((size_t)b * Lz) * Cz;
    const float* rF = resF + ((size_t)b * Lz) * Cz;
#pragma unroll
    for (int it = 0; it < 8; it++) {
        int id = it * 256 + tx, p = id >> 4, q = id & 15;
        float4 a = ((const float4*)(rF + (size_t)(t0 + p) * Cz))[q];
        float4 c = ((const float4*)(r0 + (size_t)(t0 + p) * Cz))[q];
        uint32_t lo = f2bf(fmaxf(a.x - c.x, 0.f)) | ((uint32_t)f2bf(fmaxf(a.y - c.y, 0.f)) << 16);
        uint32_t hi = f2bf(fmaxf(a.z - c.z, 0.f)) | ((uint32_t)f2bf(fmaxf(a.w - c.w, 0.f)) << 16);
        *(uint2*)(S + p * 72 + q * 4) = make_uint2(lo, hi);
    }
    __syncthreads();

    int lane = tx & 63, wave = tx >> 6;
    int col = lane & 31, kh = (lane >> 5) * 8;
    int prow = wave * 32 + col;

    floatx16 m0 = {}, m1 = {}, m2 = {}, m3 = {};
    const uint16_t* Ar = S + prow * 72 + kh;
#pragma unroll
    for (int ks = 0; ks < 4; ks++) {
        short8 a = *(const short8*)(Ar + ks * 16);
        const uint16_t* Bw = W1B + col * 64 + ks * 16 + kh;
        m0 = __builtin_amdgcn_mfma_f32_32x32x16_bf16(a, *(const short8*)(Bw + 0 * 32 * 64), m0, 0, 0, 0);
        m1 = __builtin_amdgcn_mfma_f32_32x32x16_bf16(a, *(const short8*)(Bw + 1 * 32 * 64), m1, 0, 0, 0);
        m2 = __builtin_amdgcn_mfma_f32_32x32x16_bf16(a, *(const short8*)(Bw + 2 * 32 * 64), m2, 0, 0, 0);
        m3 = __builtin_amdgcn_mfma_f32_32x32x16_bf16(a, *(const short8*)(Bw + 3 * 32 * 64), m3, 0, 0, 0);
    }
    int rrow = wave * 32 + 4 * (lane >> 5);
    float bf0 = b_fin1[col], bf1 = b_fin1[32 + col], bf2 = b_fin1[64 + col], bf3 = b_fin1[96 + col];
#pragma unroll
    for (int r = 0; r < 16; r++) {
        int pos = rrow + (r & 3) + 8 * (r >> 2);
        Mi[pos * 136 + col]      = f2bf(fmaxf(m0[r] + bf0, 0.f));
        Mi[pos * 136 + 32 + col] = f2bf(fmaxf(m1[r] + bf1, 0.f));
        Mi[pos * 136 + 64 + col] = f2bf(fmaxf(m2[r] + bf2, 0.f));
        Mi[pos * 136 + 96 + col] = f2bf(fmaxf(m3[r] + bf3, 0.f));
    }
    __syncthreads();

    floatx16 o0 = {};
    const uint16_t* Mr = Mi + prow * 136 + kh;
#pragma unroll
    for (int ks = 0; ks < 8; ks++) {
        short8 a = *(const short8*)(Mr + ks * 16);
        o0 = __builtin_amdgcn_mfma_f32_32x32x16_bf16(a, *(const short8*)(W2B + col * 128 + ks * 16 + kh), o0, 0, 0, 0);
    }
    if (col < Oz) {
        float bo = b_fin2[col];
        float* op = out + ((size_t)b * Oz + col) * Lz + t0;
#pragma unroll
        for (int r = 0; r < 16; r++) {
            int pos = rrow + (r & 3) + 8 * (r >> 2);
            op[pos] = o0[r] + bo;
        }
    }
}

// ---------------------------------------------------------------------------
extern "C" void kernel_launch(void* const* d_in, const int* in_sizes, int n_in,
                              void* d_out, int out_size, void* d_ws, size_t ws_size,
                              hipStream_t stream) {
    const int*   tok      = (const int*)d_in[0];
    const int*   gin      = (const int*)d_in[1];
    const float* table    = (const float*)d_in[2];
    const float* w_causal = (const float*)d_in[3];
    const float* b_causal = (const float*)d_in[4];
    const float* w_f      = (const float*)d_in[5];
    const float* b_f      = (const float*)d_in[6];
    const float* w_g      = (const float*)d_in[7];
    const float* b_g      = (const float*)d_in[8];
    const float* wl_f     = (const float*)d_in[9];
    const float* bl_f     = (const float*)d_in[10];
    const float* wl_g     = (const float*)d_in[11];
    const float* bl_g     = (const float*)d_in[12];
    const float* w_res    = (const float*)d_in[13];
    const float* b_res    = (const float*)d_in[14];
    const float* w_fin1   = (const float*)d_in[15];
    const float* b_fin1   = (const float*)d_in[16];
    const float* w_fin2   = (const float*)d_in[17];
    const float* b_fin2   = (const float*)d_in[18];
    float* out = (float*)d_out;

    float* ws = (float*)d_ws;
    const size_t NRES = (size_t)Bz * Lz * Cz;       // 8388608 floats
    float* resA = ws;                                // initial res (preserved)
    float* resB = ws + NRES;
    float* resC = ws + 2 * NRES;
    uint16_t* u16 = (uint16_t*)(ws + 3 * NRES);
    uint16_t* WB  = u16;                             // 147456
    uint16_t* WrB = u16 + 147456;                    // 36864
    uint16_t* W1B = u16 + 184320;                    // 8192
    uint16_t* W2B = u16 + 192512;                    // 4096  (total 196608 u16 = 98304 f)
    float* hh    = ws + 3 * NRES + 98304;            // 73728
    float* proj0 = hh + 73728;                       // 1920
    float* proj1 = proj0 + 1920;                     // 1920

    pack_k<<<776, 256, 0, stream>>>(w_f, w_g, w_res, w_fin1, w_fin2, w_causal, table,
                                    WB, WrB, W1B, W2B, proj0, proj1);
    hcomp_k<<<NDz * 2 * Bz, 256, 0, stream>>>(gin, table, wl_f, wl_g,
                                              b_f, b_g, bl_f, bl_g, hh);
    init_k<<<dim3(Lz / 16, Bz), 256, 0, stream>>>(tok, b_causal, proj0, proj1, resA);

    float* rin = resA;
    float* rout = resB;
    for (int i = 0; i < NDz; i++) {
        int d = 2 << i;                              // 2,4,...,512
        layer_k<<<dim3(Lz / 128, Bz), 256, 0, stream>>>(
            rin, rout, WB + (size_t)i * 16384, WrB + (size_t)i * 4096, hh, b_res, i, d);
        if (i == 0) { rin = resB; rout = resC; }
        else        { float* t = rin; rin = rout; rout = t; }
    }
    // rin = final res; skips = rin - resA
    final_k<<<dim3(Lz / 128, Bz), 256, 0, stream>>>(resA, rin, W1B, W2B,
                                                    b_fin1, b_fin2, out);
}

// Round 3
// 359.376 us; speedup vs baseline: 6.8634x; 1.4413x over previous
//
#include <hip/hip_runtime.h>
#include <stdint.h>

// WaveNetX forward. B=64, L=2048, V=30, E=128, G=8, C=64, F=128, O=30, K=2, ND=9.
// R2: 16x16x32 MFMA with weight A-frags held in registers; batched staging loads;
//     hcomp replaced by a packed bf16 GEMM (hhT). skips = resF - res0 (no buffer).
#define Bz 64
#define Lz 2048
#define Vz 30
#define Ez 128
#define Gz 8
#define Cz 64
#define Fz 128
#define Oz 30
#define NDz 9

typedef __attribute__((ext_vector_type(8))) short short8;   // 8 bf16 = 4 VGPR
typedef __attribute__((ext_vector_type(4))) float floatx4;  // 16x16 C/D

__device__ __forceinline__ uint16_t f2bf(float f) {         // RNE f32->bf16
    uint32_t u = __float_as_uint(f);
    u += 0x7fffu + ((u >> 16) & 1u);
    return (uint16_t)(u >> 16);
}
__device__ __forceinline__ uint32_t pack2(float a, float b) {
    return (uint32_t)f2bf(a) | ((uint32_t)f2bf(b) << 16);
}
__device__ __forceinline__ float fsig(float x) {
    x = fminf(fmaxf(x, -30.f), 30.f);
    return __builtin_amdgcn_rcpf(1.f + __expf(-x));
}
__device__ __forceinline__ float ftanh(float x) {
    x = fminf(fmaxf(x, -15.f), 15.f);
    float e = __expf(2.f * x);
    return (e - 1.f) * __builtin_amdgcn_rcpf(e + 1.f);
}

// section sizes for pack_k
#define N_WB   (NDz * 128 * 128)   // 147456
#define N_WR   (NDz * 64 * 64)     // 36864
#define N_W1   (Fz * Cz)           // 8192
#define N_W2   (32 * Fz)           // 4096
#define N_PROJ (Vz * Cz)           // 1920
#define N_WLB  (NDz * 128 * 1024)  // 1179648
#define N_EMB  (Bz * 1024)         // 65536
#define N_BIAS (NDz * 128)         // 1152

// ---------------------------------------------------------------------------
// Pack weights bf16 + projection tables + embG + biasrow.
//  WB [i][ch(128: 0-63 f, 64-127 g)][k(128: 0-63 tap t, 64-127 tap t-d)]
//  WrB[i][o][c]  W1B[f][c]  W2B[o(32,pad0)][f]
//  WLB[row = i*128 + fg*64 + c][j(1024)]   embG[b][j] bf16
//  biasrow[row] = b_(f/g)[i,c] + bl_(f/g)[i,c]
// ---------------------------------------------------------------------------
__global__ void pack_k(const float* __restrict__ w_f, const float* __restrict__ w_g,
                       const float* __restrict__ w_res, const float* __restrict__ w_fin1,
                       const float* __restrict__ w_fin2, const float* __restrict__ w_causal,
                       const float* __restrict__ table, const int* __restrict__ gin,
                       const float* __restrict__ wl_f, const float* __restrict__ wl_g,
                       const float* __restrict__ b_f, const float* __restrict__ b_g,
                       const float* __restrict__ bl_f, const float* __restrict__ bl_g,
                       uint16_t* __restrict__ WB, uint16_t* __restrict__ WrB,
                       uint16_t* __restrict__ W1B, uint16_t* __restrict__ W2B,
                       float* __restrict__ proj0, float* __restrict__ proj1,
                       uint16_t* __restrict__ WLB, uint16_t* __restrict__ embG,
                       float* __restrict__ biasrow) {
    int tid = blockIdx.x * 256 + threadIdx.x;
    if (tid < N_WB) {
        int i = tid >> 14, rem = tid & 16383, ch = rem >> 7, k = rem & 127;
        int kin = k & 63, tap = (k < 64) ? 1 : 0;
        float v = (ch < 64) ? w_f[((i * Cz + ch) * Cz + kin) * 2 + tap]
                            : w_g[((i * Cz + (ch - 64)) * Cz + kin) * 2 + tap];
        WB[tid] = f2bf(v);
        return;
    }
    tid -= N_WB;
    if (tid < N_WR) { WrB[tid] = f2bf(w_res[tid]); return; }
    tid -= N_WR;
    if (tid < N_W1) { W1B[tid] = f2bf(w_fin1[tid]); return; }
    tid -= N_W1;
    if (tid < N_W2) {
        int o = tid >> 7, f = tid & 127;
        W2B[tid] = f2bf(o < Oz ? w_fin2[o * Fz + f] : 0.f);
        return;
    }
    tid -= N_W2;
    if (tid < N_PROJ) {
        int v = tid >> 6, c = tid & 63;
        float s0 = 0.f, s1 = 0.f;
        if (v != 0) {
            for (int e = 0; e < Ez; e++) {
                float tv = table[v * Ez + e];
                s0 += w_causal[(c * Ez + e) * 2 + 0] * tv;
                s1 += w_causal[(c * Ez + e) * 2 + 1] * tv;
            }
        }
        proj0[tid] = s0; proj1[tid] = s1;
        return;
    }
    tid -= N_PROJ;
    if (tid < N_WLB) {
        int row = tid >> 10, j = tid & 1023;
        int i = row >> 7, rem = row & 127, fg = rem >> 6, c = rem & 63;
        const float* wl = fg ? wl_g : wl_f;
        WLB[tid] = f2bf(wl[((size_t)(i * Cz + c)) * 1024 + j]);
        return;
    }
    tid -= N_WLB;
    if (tid < N_EMB) {
        int b = tid >> 10, j = tid & 1023;
        int g = j >> 7, e = j & 127;
        int v = gin[b * Gz + g];
        embG[tid] = f2bf(v ? table[v * Ez + e] : 0.f);
        return;
    }
    tid -= N_EMB;
    if (tid < N_BIAS) {
        int i = tid >> 7, rem = tid & 127, fg = rem >> 6, c = rem & 63;
        biasrow[tid] = (fg ? b_g : b_f)[i * Cz + c] + (fg ? bl_g : bl_f)[i * Cz + c];
    }
}

// ---------------------------------------------------------------------------
// hhT[row(1152)][b(64)] = biasrow[row] + WLB[row,:] . embG[b,:]   (MFMA)
// 18 blocks x 4 waves; wave = 16-row m-tile, 4 n-tiles, K=1024.
// ---------------------------------------------------------------------------
__global__ __launch_bounds__(256) void hgemm_k(
    const uint16_t* __restrict__ WLB, const uint16_t* __restrict__ embG,
    const float* __restrict__ biasrow, float* __restrict__ hhT) {
    int tx = threadIdx.x, lane = tx & 63, wave = tx >> 6;
    int nl = lane & 15, quad = lane >> 4;
    int row0 = blockIdx.x * 64 + wave * 16;
    floatx4 acc[4];
    float bv[4];
#pragma unroll
    for (int r = 0; r < 4; r++) bv[r] = biasrow[row0 + quad * 4 + r];
#pragma unroll
    for (int nt = 0; nt < 4; nt++)
#pragma unroll
        for (int r = 0; r < 4; r++) acc[nt][r] = bv[r];
    const uint16_t* ap = WLB + (size_t)(row0 + nl) * 1024 + quad * 8;
#pragma unroll 4
    for (int ks = 0; ks < 32; ks++) {
        short8 a = *(const short8*)(ap + ks * 32);
#pragma unroll
        for (int nt = 0; nt < 4; nt++) {
            short8 bb = *(const short8*)(embG + (size_t)(nt * 16 + nl) * 1024 + ks * 32 + quad * 8);
            acc[nt] = __builtin_amdgcn_mfma_f32_16x16x32_bf16(a, bb, acc[nt], 0, 0, 0);
        }
    }
#pragma unroll
    for (int nt = 0; nt < 4; nt++)
#pragma unroll
        for (int r = 0; r < 4; r++)
            hhT[(size_t)(row0 + quad * 4 + r) * 64 + nt * 16 + nl] = acc[nt][r];
}

// ---------------------------------------------------------------------------
// Initial conv as token lookup; res layout [b][t][c].
// ---------------------------------------------------------------------------
__global__ __launch_bounds__(256) void init_k(
    const int* __restrict__ tok, const float* __restrict__ b_causal,
    const float* __restrict__ proj0, const float* __restrict__ proj1,
    float* __restrict__ res) {
    int tx = threadIdx.x;
    int q = tx & 15, tl = tx >> 4;
    int b = blockIdx.y;
    int t = blockIdx.x * 16 + tl;
    int v1 = tok[b * Lz + t];
    int v0 = (t > 0) ? tok[b * Lz + t - 1] : 0;   // proj0 row 0 is zero
    float4 p1 = ((const float4*)(proj1 + v1 * Cz))[q];
    float4 p0 = ((const float4*)(proj0 + v0 * Cz))[q];
    float4 bc = ((const float4*)b_causal)[q];
    float4 r;
    r.x = p1.x + p0.x + bc.x; r.y = p1.y + p0.y + bc.y;
    r.z = p1.z + p0.z + bc.z; r.w = p1.w + p0.w + bc.w;
    ((float4*)(res + ((size_t)(b * Lz + t)) * Cz))[q] = r;
}

// ---------------------------------------------------------------------------
// One layer. Block = 128 pos x 1 batch, 4 waves, 16x16x32 MFMA.
// C[m=ch][n=pos]; wave w owns f-ch/g-ch [w*16,(w+1)*16) -> gate in-lane.
// Weight A-frags in registers for the whole block (40 VGPR).
// ---------------------------------------------------------------------------
__global__ __launch_bounds__(256, 3) void layer_k(
    const float* __restrict__ rin, float* __restrict__ rout,
    const uint16_t* __restrict__ WBl, const uint16_t* __restrict__ WrBl,
    const float* __restrict__ hhT, const float* __restrict__ b_res,
    int i, int d) {
    __shared__ __align__(16) uint16_t X[128 * 136];   // [pos][k] pad->136 (272B rows)
    __shared__ __align__(16) uint16_t Z[128 * 72];    // [pos][c]  pad->72 (144B rows)
    int tx = threadIdx.x;
    int lane = tx & 63, wave = tx >> 6;
    int nl = lane & 15, quad = lane >> 4;
    int b = blockIdx.y, t0 = blockIdx.x * 128;
    const float* rbase = rin + ((size_t)b * Lz) * Cz;

    // ---- staging loads: all 16 float4 in flight before converting ----
    float4 va[8], vb[8];
#pragma unroll
    for (int it = 0; it < 8; it++) {
        int id = it * 256 + tx, pp = id >> 4, qq = id & 15;
        va[it] = ((const float4*)(rbase + (size_t)(t0 + pp) * Cz))[qq];
    }
#pragma unroll
    for (int it = 0; it < 8; it++) {
        int id = it * 256 + tx, pp = id >> 4, qq = id & 15;
        int t = t0 + pp - d;
        vb[it] = (t >= 0) ? ((const float4*)(rbase + (size_t)t * Cz))[qq]
                          : make_float4(0.f, 0.f, 0.f, 0.f);
    }

    // ---- weight A-frags (registers, block lifetime) ----
    short8 AF[4], AG[4], AR[2];
    {
        const uint16_t* wf = WBl + (wave * 16 + nl) * 128 + quad * 8;
#pragma unroll
        for (int ks = 0; ks < 4; ks++) {
            AF[ks] = *(const short8*)(wf + ks * 32);
            AG[ks] = *(const short8*)(wf + 64 * 128 + ks * 32);
        }
        const uint16_t* wr = WrBl + (wave * 16 + nl) * 64 + quad * 8;
#pragma unroll
        for (int ks = 0; ks < 2; ks++) AR[ks] = *(const short8*)(wr + ks * 32);
    }
    // conditioning (acc init) + skip bias
    float hfv[4], hgv[4], brv[4];
    {
        const float* hp = hhT + ((size_t)(i * 128 + wave * 16 + quad * 4)) * 64 + b;
#pragma unroll
        for (int r = 0; r < 4; r++) {
            hfv[r] = hp[r * 64];
            hgv[r] = hp[4096 + r * 64];        // g rows are +64 rows
        }
        const float* brp = b_res + i * Cz + wave * 16 + quad * 4;
#pragma unroll
        for (int r = 0; r < 4; r++) brv[r] = brp[r];
    }

    // ---- convert + LDS write ----
#pragma unroll
    for (int it = 0; it < 8; it++) {
        int id = it * 256 + tx, pp = id >> 4, qq = id & 15;
        uint16_t* xr = X + pp * 136 + qq * 4;
        *(uint2*)xr = make_uint2(pack2(va[it].x, va[it].y), pack2(va[it].z, va[it].w));
        *(uint2*)(xr + 64) = make_uint2(pack2(vb[it].x, vb[it].y), pack2(vb[it].z, vb[it].w));
    }
    __syncthreads();

    // ---- GEMM1: acc[ch][pos] over K=128 ----
    floatx4 accF[8], accG[8];
#pragma unroll
    for (int nt = 0; nt < 8; nt++)
#pragma unroll
        for (int r = 0; r < 4; r++) { accF[nt][r] = hfv[r]; accG[nt][r] = hgv[r]; }
#pragma unroll
    for (int nt = 0; nt < 8; nt++) {
        const uint16_t* xp = X + (nt * 16 + nl) * 136 + quad * 8;
#pragma unroll
        for (int ks = 0; ks < 4; ks++) {
            short8 bf = *(const short8*)(xp + ks * 32);
            accF[nt] = __builtin_amdgcn_mfma_f32_16x16x32_bf16(AF[ks], bf, accF[nt], 0, 0, 0);
            accG[nt] = __builtin_amdgcn_mfma_f32_16x16x32_bf16(AG[ks], bf, accG[nt], 0, 0, 0);
        }
    }

    // ---- gate -> Z ----
    int chq = wave * 16 + quad * 4;
#pragma unroll
    for (int nt = 0; nt < 8; nt++) {
        int pos = nt * 16 + nl;
        float z0 = ftanh(accF[nt][0]) * fsig(accG[nt][0]);
        float z1 = ftanh(accF[nt][1]) * fsig(accG[nt][1]);
        float z2 = ftanh(accF[nt][2]) * fsig(accG[nt][2]);
        float z3 = ftanh(accF[nt][3]) * fsig(accG[nt][3]);
        *(uint2*)(Z + pos * 72 + chq) = make_uint2(pack2(z0, z1), pack2(z2, z3));
    }
    __syncthreads();

    // ---- GEMM2: skip[o][pos] over K=64 ----
    floatx4 acc2[8];
#pragma unroll
    for (int nt = 0; nt < 8; nt++)
#pragma unroll
        for (int r = 0; r < 4; r++) acc2[nt][r] = brv[r];
#pragma unroll
    for (int nt = 0; nt < 8; nt++) {
        const uint16_t* zp = Z + (nt * 16 + nl) * 72 + quad * 8;
        acc2[nt] = __builtin_amdgcn_mfma_f32_16x16x32_bf16(AR[0], *(const short8*)zp, acc2[nt], 0, 0, 0);
        acc2[nt] = __builtin_amdgcn_mfma_f32_16x16x32_bf16(AR[1], *(const short8*)(zp + 32), acc2[nt], 0, 0, 0);
    }

    // ---- epilogue: rout = rin + skip (float4, fully-covered 64B lines) ----
    float* ro = rout + ((size_t)b * Lz) * Cz;
#pragma unroll
    for (int nt = 0; nt < 8; nt++) {
        size_t off = (size_t)(t0 + nt * 16 + nl) * Cz + chq;
        float4 rv = *(const float4*)(rbase + off);
        float4 ov;
        ov.x = rv.x + acc2[nt][0];
        ov.y = rv.y + acc2[nt][1];
        ov.z = rv.z + acc2[nt][2];
        ov.w = rv.w + acc2[nt][3];
        *(float4*)(ro + off) = ov;
    }
}

// ---------------------------------------------------------------------------
// Head: s = relu(resF-res0); mid = relu(W1 s + b1); out = W2 mid + b2.
// ---------------------------------------------------------------------------
__global__ __launch_bounds__(256, 3) void final_k(
    const float* __restrict__ res0, const float* __restrict__ resF,
    const uint16_t* __restrict__ W1B, const uint16_t* __restrict__ W2B,
    const float* __restrict__ b_fin1, const float* __restrict__ b_fin2,
    float* __restrict__ out) {
    __shared__ __align__(16) uint16_t S[128 * 72];
    __shared__ __align__(16) uint16_t Mi[128 * 136];
    int tx = threadIdx.x;
    int lane = tx & 63, wave = tx >> 6;
    int nl = lane & 15, quad = lane >> 4;
    int b = blockIdx.y, t0 = blockIdx.x * 128;
    const float* r0 = res0 + ((size_t)b * Lz) * Cz;
    const float* rF = resF + ((size_t)b * Lz) * Cz;

    float4 va[8], vb[8];
#pragma unroll
    for (int it = 0; it < 8; it++) {
        int id = it * 256 + tx, pp = id >> 4, qq = id & 15;
        va[it] = ((const float4*)(rF + (size_t)(t0 + pp) * Cz))[qq];
        vb[it] = ((const float4*)(r0 + (size_t)(t0 + pp) * Cz))[qq];
    }
    // weight A-frags
    short8 A1[2][2], A2[2][4];
#pragma unroll
    for (int mt = 0; mt < 2; mt++) {
        const uint16_t* w1 = W1B + (wave * 32 + mt * 16 + nl) * 64 + quad * 8;
#pragma unroll
        for (int ks = 0; ks < 2; ks++) A1[mt][ks] = *(const short8*)(w1 + ks * 32);
        const uint16_t* w2 = W2B + (mt * 16 + nl) * 128 + quad * 8;
#pragma unroll
        for (int ks = 0; ks < 4; ks++) A2[mt][ks] = *(const short8*)(w2 + ks * 32);
    }
#pragma unroll
    for (int it = 0; it < 8; it++) {
        int id = it * 256 + tx, pp = id >> 4, qq = id & 15;
        float sx = fmaxf(va[it].x - vb[it].x, 0.f), sy = fmaxf(va[it].y - vb[it].y, 0.f);
        float sz = fmaxf(va[it].z - vb[it].z, 0.f), sw = fmaxf(va[it].w - vb[it].w, 0.f);
        *(uint2*)(S + pp * 72 + qq * 4) = make_uint2(pack2(sx, sy), pack2(sz, sw));
    }
    __syncthreads();

    // GEMM1: mid[f][pos], K=64; wave owns f-tiles wave*32 + {0,16}
    floatx4 accM[2][8];
    float b1v[2][4];
#pragma unroll
    for (int mt = 0; mt < 2; mt++)
#pragma unroll
        for (int r = 0; r < 4; r++) b1v[mt][r] = b_fin1[wave * 32 + mt * 16 + quad * 4 + r];
#pragma unroll
    for (int mt = 0; mt < 2; mt++)
#pragma unroll
        for (int nt = 0; nt < 8; nt++)
#pragma unroll
            for (int r = 0; r < 4; r++) accM[mt][nt][r] = b1v[mt][r];
#pragma unroll
    for (int nt = 0; nt < 8; nt++) {
        const uint16_t* sp = S + (nt * 16 + nl) * 72 + quad * 8;
#pragma unroll
        for (int ks = 0; ks < 2; ks++) {
            short8 s = *(const short8*)(sp + ks * 32);
            accM[0][nt] = __builtin_amdgcn_mfma_f32_16x16x32_bf16(A1[0][ks], s, accM[0][nt], 0, 0, 0);
            accM[1][nt] = __builtin_amdgcn_mfma_f32_16x16x32_bf16(A1[1][ks], s, accM[1][nt], 0, 0, 0);
        }
    }
#pragma unroll
    for (int mt = 0; mt < 2; mt++)
#pragma unroll
        for (int nt = 0; nt < 8; nt++) {
            int pos = nt * 16 + nl;
            int fq = wave * 32 + mt * 16 + quad * 4;
            float m0 = fmaxf(accM[mt][nt][0], 0.f), m1 = fmaxf(accM[mt][nt][1], 0.f);
            float m2 = fmaxf(accM[mt][nt][2], 0.f), m3 = fmaxf(accM[mt][nt][3], 0.f);
            *(uint2*)(Mi + pos * 136 + fq) = make_uint2(pack2(m0, m1), pack2(m2, m3));
        }
    __syncthreads();

    // GEMM2: out[o(32)][pos], K=128; wave owns pos-tiles {2w, 2w+1}
    floatx4 accO[2][2];
#pragma unroll
    for (int mt = 0; mt < 2; mt++)
#pragma unroll
        for (int r = 0; r < 4; r++) {
            int o = mt * 16 + quad * 4 + r;
            float bo = (o < Oz) ? b_fin2[o] : 0.f;
            accO[mt][0][r] = bo; accO[mt][1][r] = bo;
        }
#pragma unroll
    for (int ntl = 0; ntl < 2; ntl++) {
        int nt = wave * 2 + ntl;
        const uint16_t* mp = Mi + (nt * 16 + nl) * 136 + quad * 8;
#pragma unroll
        for (int ks = 0; ks < 4; ks++) {
            short8 m = *(const short8*)(mp + ks * 32);
            accO[0][ntl] = __builtin_amdgcn_mfma_f32_16x16x32_bf16(A2[0][ks], m, accO[0][ntl], 0, 0, 0);
            accO[1][ntl] = __builtin_amdgcn_mfma_f32_16x16x32_bf16(A2[1][ks], m, accO[1][ntl], 0, 0, 0);
        }
    }
#pragma unroll
    for (int mt = 0; mt < 2; mt++)
#pragma unroll
        for (int ntl = 0; ntl < 2; ntl++)
#pragma unroll
            for (int r = 0; r < 4; r++) {
                int o = mt * 16 + quad * 4 + r;
                if (o < Oz)
                    out[((size_t)b * Oz + o) * Lz + t0 + (wave * 2 + ntl) * 16 + nl] =
                        accO[mt][ntl][r];
            }
}

// ---------------------------------------------------------------------------
extern "C" void kernel_launch(void* const* d_in, const int* in_sizes, int n_in,
                              void* d_out, int out_size, void* d_ws, size_t ws_size,
                              hipStream_t stream) {
    const int*   tok      = (const int*)d_in[0];
    const int*   gin      = (const int*)d_in[1];
    const float* table    = (const float*)d_in[2];
    const float* w_causal = (const float*)d_in[3];
    const float* b_causal = (const float*)d_in[4];
    const float* w_f      = (const float*)d_in[5];
    const float* b_f      = (const float*)d_in[6];
    const float* w_g      = (const float*)d_in[7];
    const float* b_g      = (const float*)d_in[8];
    const float* wl_f     = (const float*)d_in[9];
    const float* bl_f     = (const float*)d_in[10];
    const float* wl_g     = (const float*)d_in[11];
    const float* bl_g     = (const float*)d_in[12];
    const float* w_res    = (const float*)d_in[13];
    const float* b_res    = (const float*)d_in[14];
    const float* w_fin1   = (const float*)d_in[15];
    const float* b_fin1   = (const float*)d_in[16];
    const float* w_fin2   = (const float*)d_in[17];
    const float* b_fin2   = (const float*)d_in[18];
    float* out = (float*)d_out;

    float* ws = (float*)d_ws;
    const size_t NRES = (size_t)Bz * Lz * Cz;        // 8388608 floats
    float* resA = ws;                                 // initial res (kept for head)
    float* resB = ws + NRES;
    float* resC = ws + 2 * NRES;
    uint16_t* u16 = (uint16_t*)(ws + 3 * NRES);
    uint16_t* WB  = u16;                              // 147456
    uint16_t* WrB = WB + N_WB;                        // 36864
    uint16_t* W1B = WrB + N_WR;                       // 8192
    uint16_t* W2B = W1B + N_W1;                       // 4096
    uint16_t* WLB = W2B + N_W2;                       // 1179648
    uint16_t* embG = WLB + N_WLB;                     // 65536  (u16 total 1441792)
    float* fbase   = ws + 3 * NRES + 1441792 / 2;
    float* hhT     = fbase;                           // 73728
    float* proj0   = hhT + 73728;                     // 1920
    float* proj1   = proj0 + N_PROJ;                  // 1920
    float* biasrow = proj1 + N_PROJ;                  // 1152

    int npack = N_WB + N_WR + N_W1 + N_W2 + N_PROJ + N_WLB + N_EMB + N_BIAS;
    pack_k<<<(npack + 255) / 256, 256, 0, stream>>>(
        w_f, w_g, w_res, w_fin1, w_fin2, w_causal, table, gin,
        wl_f, wl_g, b_f, b_g, bl_f, bl_g,
        WB, WrB, W1B, W2B, proj0, proj1, WLB, embG, biasrow);
    hgemm_k<<<18, 256, 0, stream>>>(WLB, embG, biasrow, hhT);
    init_k<<<dim3(Lz / 16, Bz), 256, 0, stream>>>(tok, b_causal, proj0, proj1, resA);

    float* rin = resA;
    float* rout = resB;
    for (int i = 0; i < NDz; i++) {
        int d = 2 << i;                               // 2,4,...,512
        layer_k<<<dim3(Lz / 128, Bz), 256, 0, stream>>>(
            rin, rout, WB + (size_t)i * 16384, WrB + (size_t)i * 4096, hhT, b_res, i, d);
        if (i == 0) { rin = resB; rout = resC; }
        else        { float* t = rin; rin = rout; rout = t; }
    }
    // rin = final res; skips = rin - resA
    final_k<<<dim3(Lz / 128, Bz), 256, 0, stream>>>(resA, rin, W1B, W2B,
                                                    b_fin1, b_fin2, out);
}